// Round 7
// baseline (305.187 us; speedup 1.0000x reference)
//
#include <hip/hip_runtime.h>

typedef unsigned short u16;
typedef short bf16x8 __attribute__((ext_vector_type(8)));
typedef float f32x4 __attribute__((ext_vector_type(4)));

#define NF 65536
#define NSC 1024     // sub-chunks of 64 frames
#define NMAC 16      // macros of 64 sub-chunks

__device__ __forceinline__ float sigm(float x){ return 1.0f/(1.0f+__expf(-x)); }

__device__ __forceinline__ u16 f2bf(float f){
  union { float f; unsigned u; } v; v.f = f;
  unsigned r = (v.u + 0x7fffu + ((v.u >> 16) & 1u)) >> 16;   // RNE
  return (u16)r;
}
__device__ __forceinline__ float bfl(unsigned p){ union{unsigned u; float f;} v; v.u = p<<16;          return v.f; }
__device__ __forceinline__ float bfh(unsigned p){ union{unsigned u; float f;} v; v.u = p & 0xffff0000u; return v.f; }

// ---------------- prep: pack W1, W2 into MFMA fragment-ready bf16 layouts.
__global__ __launch_bounds__(256) void k_prep(const float* __restrict__ W1, const float* __restrict__ W2,
                                              u16* __restrict__ W1f, u16* __restrict__ W2f){
  int idx = blockIdx.x*256 + threadIdx.x;     // 0..131071
  {
    int j  = idx & 7;
    int L  = (idx >> 3) & 63;
    int ks = (idx >> 9) & 1;
    int rt = (idx >> 10) & 15;
    int ck = idx >> 14;
    int row = 16*rt + (L & 15);
    int k   = ck*64 + ks*32 + ((L >> 4) << 3) + j;
    W1f[idx] = f2bf(W1[row*512 + k]);
  }
  if (idx < 32768){
    int j  = idx & 7;
    int L  = (idx >> 3) & 63;
    int ks = (idx >> 9) & 3;
    int rt = idx >> 11;
    int row = 16*rt + (L & 15);
    int m   = ks*32 + ((L >> 4) << 3) + j;
    W2f[idx] = f2bf(W2[row*128 + m]);
  }
}

// ---------------- GEMM1: 256 rows x 64 frames per block, K=512, grid 1024.
// T14 reg-staged x (loads survive barriers; ds_write one phase later), W1f
// frags from L2, fused transpose+convert, fused sub-chunk affine reduce.
// a,b stored as packed bf16 pairs (u32) to halve AB traffic.
__global__ __launch_bounds__(256, 4) void k_gemm1(const float* __restrict__ x,
        const u16* __restrict__ W1f, const float* __restrict__ B1,
        unsigned* __restrict__ AB,
        float* __restrict__ Ac, float* __restrict__ Bc){
  __shared__ __align__(16) float ls[8192];     // 2 x 16 KB: x chunk fp32 [64 k][64 t]
  __shared__ __align__(16) u16  xs[4096];      // 8 KB: [c 0..3][ks 0..1][lane][8]
  const int tid = threadIdx.x;
  const int wv = tid >> 6, L = tid & 63;
  const int q = L >> 4, ln = L & 15;
  const int g = blockIdx.x;                    // sub-chunk id
  const int F0 = g * 64;
  const int rt0 = 2*wv;
  const bf16x8* W1f8 = (const bf16x8*)W1f;

  f32x4 acc[4][4];
  #pragma unroll
  for (int a=0;a<4;a++)
    #pragma unroll
    for (int c=0;c<4;c++) acc[a][c] = (f32x4){0.f,0.f,0.f,0.f};

  // reg-staging slots: thread (wv,i,q,ln) owns row 16*wv+4*i+q, cols ln*4..+3
  #define XSRC(ck,i) ((const float4*)(x + (size_t)((ck)*64 + 16*wv + 4*(i) + q)*NF + F0 + ln*4))
  #define LDST(buf,i) ((float4*)(ls + (buf)*4096 + (wv*4+(i))*256 + (size_t)L*4))
  float4 vst[4];
  #pragma unroll
  for (int i=0;i<4;i++) vst[i] = *XSRC(0,i);
  #pragma unroll
  for (int i=0;i<4;i++) *LDST(0,i) = vst[i];
  #pragma unroll
  for (int i=0;i<4;i++) vst[i] = *XSRC(1,i);   // in flight across ck=0

  for (int ck=0; ck<8; ++ck){
    // W1 fragments straight from L2 (W1f is 256 KB, hot); consumed after barrier2
    bf16x8 af[2][4];
    #pragma unroll
    for (int ks=0;ks<2;ks++){
      af[ks][0] = W1f8[ck*2048 + ((rt0  )*2+ks)*64 + L];
      af[ks][1] = W1f8[ck*2048 + ((rt0+1)*2+ks)*64 + L];
      af[ks][2] = W1f8[ck*2048 + ((rt0+8)*2+ks)*64 + L];
      af[ks][3] = W1f8[ck*2048 + ((rt0+9)*2+ks)*64 + L];
    }
    __syncthreads();                           // buf[ck&1] ds_writes visible
    // transpose-convert ls[ck&1] -> xs; 2 slots/thread, 8 elems each
    // slot bits: [3:0]=lns [5:4]=cc [7:6]=qs [8]=kss ; banks 2-way max (free)
    {
      const float* lsb = ls + (ck&1)*4096;
      #pragma unroll
      for (int i=0;i<2;i++){
        int s    = tid + 256*i;
        int lns  = s & 15;
        int cc   = (s >> 4) & 3;
        int qs   = (s >> 6) & 3;
        int kss  = (s >> 8) & 1;
        const float* rp = lsb + (kss*32 + qs*8)*64 + cc*16 + lns;
        unsigned u[8];
        #pragma unroll
        for (int j=0;j<8;j++) u[j] = f2bf(rp[j*64]);
        uint4 pk;
        pk.x = u[0] | (u[1]<<16); pk.y = u[2] | (u[3]<<16);
        pk.z = u[4] | (u[5]<<16); pk.w = u[6] | (u[7]<<16);
        *(uint4*)(xs + ((cc*2+kss)*64 + qs*16 + lns)*8) = pk;
      }
    }
    __syncthreads();                           // xs ready
    // stage ck+1 into the other buffer (WAR-safe: last read 2 barriers ago);
    // the ds_write's implicit wait covers vst's loads, issued a full phase ago.
    if (ck < 7){
      #pragma unroll
      for (int i=0;i<4;i++) *LDST((ck+1)&1, i) = vst[i];
      if (ck < 6){
        #pragma unroll
        for (int i=0;i<4;i++) vst[i] = *XSRC(ck+2, i);
      }
    }
    #pragma unroll
    for (int ks=0; ks<2; ++ks){
      #pragma unroll
      for (int c=0;c<4;c++){
        bf16x8 bf = ((const bf16x8*)xs)[(c*2+ks)*64 + L];
        acc[0][c] = __builtin_amdgcn_mfma_f32_16x16x32_bf16(af[ks][0], bf, acc[0][c], 0,0,0);
        acc[1][c] = __builtin_amdgcn_mfma_f32_16x16x32_bf16(af[ks][1], bf, acc[1][c], 0,0,0);
        acc[2][c] = __builtin_amdgcn_mfma_f32_16x16x32_bf16(af[ks][2], bf, acc[2][c], 0,0,0);
        acc[3][c] = __builtin_amdgcn_mfma_f32_16x16x32_bf16(af[ks][3], bf, acc[3][c], 0,0,0);
      }
    }
  }
  #undef XSRC
  #undef LDST

  // epilogue: sigmoid, a = le*ri, b = 1-le; pack (bf16 a | bf16 b<<16) -> AB;
  // fused sub-chunk reduce computed from the ROUNDED a,b so the carry path is
  // exactly consistent with k_apply's recompute.
  float bl[2][4], br[2][4], RA[2][4], RB[2][4];
  #pragma unroll
  for (int pr=0;pr<2;pr++){
    int mb = 32*wv + 16*pr + 4*q;
    #pragma unroll
    for (int r=0;r<4;r++){ bl[pr][r] = B1[mb+r]; br[pr][r] = B1[mb+128+r]; }
  }
  #pragma unroll
  for (int c=0;c<4;c++){
    int t = F0 + 16*c + ln;
    #pragma unroll
    for (int pr=0;pr<2;pr++){
      int mb = 32*wv + 16*pr + 4*q;
      f32x4 Lv = acc[pr][c], Rv = acc[pr+2][c];
      unsigned p4[4];
      float ar[4], brr[4];
      #pragma unroll
      for (int r=0;r<4;r++){
        float le = sigm(Lv[r] + bl[pr][r]);
        float ri = sigm(Rv[r] + br[pr][r]);
        unsigned pa = f2bf(le*ri), pb = f2bf(1.0f - le);
        p4[r] = pa | (pb<<16);
        ar[r] = bfl(p4[r]); brr[r] = bfh(p4[r]);   // rounded values for the reduce
      }
      *(uint4*)(AB + (size_t)t*128 + mb) = make_uint4(p4[0],p4[1],p4[2],p4[3]);
      #pragma unroll
      for (int r=0;r<4;r++){
        float As = ar[r], Bs = brr[r];
        #pragma unroll
        for (int d=1; d<16; d<<=1){
          float Ap = __shfl_xor(As, d);
          float Bp = __shfl_xor(Bs, d);
          Bs = (ln & d) ? fmaf(As, Bp, Bs) : fmaf(Ap, Bs, Bp);
          As *= Ap;
        }
        if (c == 0){ RA[pr][r] = As; RB[pr][r] = Bs; }
        else       { RB[pr][r] = fmaf(As, RB[pr][r], Bs); RA[pr][r] *= As; }
      }
    }
  }
  if (ln == 0){
    #pragma unroll
    for (int pr=0;pr<2;pr++){
      int mb = 32*wv + 16*pr + 4*q;
      #pragma unroll
      for (int r=0;r<4;r++){
        Ac[g*128 + mb + r] = RA[pr][r];
        Bc[g*128 + mb + r] = RB[pr][r];
      }
    }
  }
}

// ---------------- macro totals: 16 blocks, each composes 64 sub-chunks
__global__ __launch_bounds__(256) void k_scan(const float* __restrict__ Ac, const float* __restrict__ Bc,
                                              float* __restrict__ MtA, float* __restrict__ MtB){
  __shared__ float sA[2][128], sB[2][128];
  const int j = blockIdx.x;
  const int m = threadIdx.x & 127, s4 = threadIdx.x >> 7;
  const int c0 = j*64 + s4*32;
  float A = 1.f, B = 0.f;
  #pragma unroll 8
  for (int i=0;i<32;i++){
    float a = Ac[(c0+i)*128 + m], b = Bc[(c0+i)*128 + m];
    B = fmaf(a, B, b);
    A *= a;
  }
  sA[s4][m] = A; sB[s4][m] = B;
  __syncthreads();
  if (s4 == 0){
    MtA[j*128+m] = sA[1][m] * sA[0][m];
    MtB[j*128+m] = fmaf(sA[1][m], sB[0][m], sB[1][m]);
  }
}

// ---------------- apply: 64 frames per block, grid 1024.
// phase 0: macro-prefix (<=15 L2-hot steps) + in-macro scan (<=31 steps, 2 segs)
// phase 1: z recompute from packed bf16 AB (2 segs x 32 frames) into zf;
// then MFMA GEMM2 + epilogue.
__global__ __launch_bounds__(256, 4) void k_apply(const unsigned* __restrict__ AB,
        const float* __restrict__ Ac, const float* __restrict__ Bc,
        const float* __restrict__ MtA, const float* __restrict__ MtB,
        const u16* __restrict__ W2f, const float* __restrict__ B2,
        float* __restrict__ out){
  __shared__ __align__(16) u16 zf[8192];       // 16 KB: [c 0..3][ks 0..3][lane][8]
  __shared__ float sA[2][128], sB[2][128];
  const int tid = threadIdx.x;
  const int g = blockIdx.x, T0 = g*64;
  const int m = tid & 127, s4 = tid >> 7;

  // phase 0: value entering sub-chunk g
  float vg;
  {
    const int j = g >> 6, r0 = j << 6, n = g & 63;
    int c0 = r0 + s4*32, c1 = r0 + n; if (c1 > c0+32) c1 = c0+32;
    float A = 1.f, B = 0.f;
    for (int c = c0; c < c1; ++c){
      float a = Ac[c*128 + m], b = Bc[c*128 + m];
      B = fmaf(a, B, b);
      A *= a;
    }
    sA[s4][m] = A; sB[s4][m] = B;              // empty segment = identity
    float v = 0.f;
    for (int jj=0; jj<j; ++jj) v = fmaf(MtA[jj*128+m], v, MtB[jj*128+m]);
    __syncthreads();
    v = fmaf(sA[0][m], v, sB[0][m]);
    v = fmaf(sA[1][m], v, sB[1][m]);
    vg = v;
    __syncthreads();                           // before sA/sB reuse
  }

  // phase 1: thread (m, s4) owns frames [32*s4, 32*s4+32) of this sub-chunk
  {
    const unsigned* abp = AB + (size_t)(T0 + s4*32)*128 + m;
    unsigned abreg[32];
    #pragma unroll
    for (int i=0;i<32;i++) abreg[i] = abp[(size_t)i*128];
    float A = 1.f, Bv = 0.f;
    #pragma unroll
    for (int i=0;i<32;i++){ Bv = fmaf(bfl(abreg[i]), Bv, bfh(abreg[i])); A *= bfl(abreg[i]); }
    sA[s4][m] = A; sB[s4][m] = Bv;
    __syncthreads();
    float v = vg;
    if (s4 == 1) v = fmaf(sA[0][m], v, sB[0][m]);
    const int base_m = (m>>5)*512 + ((m>>3)&3)*128 + (m&7);
    #pragma unroll
    for (int i=0;i<32;i++){
      int t = s4*32 + i;
      zf[base_m + (t>>4)*2048 + (t&15)*8] = f2bf(v);
      v = fmaf(bfl(abreg[i]), v, bfh(abreg[i]));
    }
  }
  __syncthreads();

  // GEMM2: 4 waves x 4 row-tiles each x 4 c-tiles, K=128
  const int wv = tid >> 6, L = tid & 63;
  const int q = L >> 4, ln = L & 15;
  f32x4 acc[4][4];
  #pragma unroll
  for (int a=0;a<4;a++)
    #pragma unroll
    for (int c=0;c<4;c++) acc[a][c] = (f32x4){0.f,0.f,0.f,0.f};

  #pragma unroll
  for (int ks=0; ks<4; ++ks){
    bf16x8 af[4];
    #pragma unroll
    for (int a=0;a<4;a++) af[a] = ((const bf16x8*)W2f)[((4*wv+a)*4+ks)*64 + L]; // L2-hot
    #pragma unroll
    for (int c=0;c<4;c++){
      bf16x8 bf = ((const bf16x8*)zf)[(c*4+ks)*64 + L];
      #pragma unroll
      for (int a=0;a<4;a++)
        acc[a][c] = __builtin_amdgcn_mfma_f32_16x16x32_bf16(af[a], bf, acc[a][c], 0,0,0);
    }
  }

  #pragma unroll
  for (int a=0;a<4;a++){
    int rowb = (4*wv+a)*16 + q*4;
    float b2[4];
    #pragma unroll
    for (int r=0;r<4;r++) b2[r] = B2[rowb+r];
    #pragma unroll
    for (int r=0;r<4;r++){
      #pragma unroll
      for (int c=0;c<4;c++)
        out[(size_t)(rowb+r)*NF + T0 + 16*c + ln] = sigm(-(acc[a][c][r] + b2[r]));
    }
  }
}

extern "C" void kernel_launch(void* const* d_in, const int* in_sizes, int n_in,
                              void* d_out, int out_size, void* d_ws, size_t ws_size,
                              hipStream_t stream) {
  const float* x  = (const float*)d_in[0];   // (512, 65536)
  const float* W1 = (const float*)d_in[1];   // (256, 512)
  const float* B1 = (const float*)d_in[2];   // (256, 1)
  const float* W2 = (const float*)d_in[3];   // (256, 128)
  const float* B2 = (const float*)d_in[4];   // (256, 1)
  float* out = (float*)d_out;                // (256, 65536) = 64 MB

  u16*      W1f = (u16*)d_ws;                // 131072 u16 (256 KB)
  u16*      W2f = W1f + 131072;              // 32768 u16 (64 KB)
  unsigned* AB  = (unsigned*)d_ws + 81920;   // NF*128 u32 = 32 MB
  float*    Ac  = (float*)(AB + (size_t)NF*128);  // 1024*128
  float*    Bc  = Ac + (size_t)NSC*128;
  float*    MtA = Bc + (size_t)NSC*128;      // 16*128
  float*    MtB = MtA + (size_t)NMAC*128;

  k_prep <<<512, 256, 0, stream>>>(W1, W2, W1f, W2f);
  k_gemm1<<<NSC, 256, 0, stream>>>(x, W1f, B1, AB, Ac, Bc);
  k_scan <<<NMAC, 256, 0, stream>>>(Ac, Bc, MtA, MtB);
  k_apply<<<NSC, 256, 0, stream>>>(AB, Ac, Bc, MtA, MtB, W2f, B2, out);
}

// Round 9
// 277.262 us; speedup vs baseline: 1.1007x; 1.1007x over previous
//
#include <hip/hip_runtime.h>

typedef unsigned short u16;
typedef short bf16x8 __attribute__((ext_vector_type(8)));
typedef float f32x4 __attribute__((ext_vector_type(4)));

#define NF 65536
#define NSC 1024     // sub-chunks of 64 frames
#define NMAC 16      // macros of 64 sub-chunks

__device__ __forceinline__ float sigm(float x){ return 1.0f/(1.0f+__expf(-x)); }

__device__ __forceinline__ u16 f2bf(float f){
  union { float f; unsigned u; } v; v.f = f;
  unsigned r = (v.u + 0x7fffu + ((v.u >> 16) & 1u)) >> 16;   // RNE
  return (u16)r;
}
__device__ __forceinline__ float bfl(unsigned p){ union{unsigned u; float f;} v; v.u = p<<16;          return v.f; }
__device__ __forceinline__ float bfh(unsigned p){ union{unsigned u; float f;} v; v.u = p & 0xffff0000u; return v.f; }

#define AS1(p) ((const __attribute__((address_space(1))) unsigned int*)(p))
#define AS3(p) ((__attribute__((address_space(3))) unsigned int*)(p))

// ---------------- prep: pack W1, W2 into MFMA fragment-ready bf16 layouts.
__global__ __launch_bounds__(256) void k_prep(const float* __restrict__ W1, const float* __restrict__ W2,
                                              u16* __restrict__ W1f, u16* __restrict__ W2f){
  int idx = blockIdx.x*256 + threadIdx.x;     // 0..131071
  {
    int j  = idx & 7;
    int L  = (idx >> 3) & 63;
    int ks = (idx >> 9) & 1;
    int rt = (idx >> 10) & 15;
    int ck = idx >> 14;
    int row = 16*rt + (L & 15);
    int k   = ck*64 + ks*32 + ((L >> 4) << 3) + j;
    W1f[idx] = f2bf(W1[row*512 + k]);
  }
  if (idx < 32768){
    int j  = idx & 7;
    int L  = (idx >> 3) & 63;
    int ks = (idx >> 9) & 3;
    int rt = idx >> 11;
    int row = 16*rt + (L & 15);
    int m   = ks*32 + ((L >> 4) << 3) + j;
    W2f[idx] = f2bf(W2[row*128 + m]);
  }
}

// ---------------- GEMM1: 256 rows x 64 frames per block, K=512, grid 1024.
// XCD-clustered blocks (contiguous frame range per XCD -> DRAM page locality).
// global_load_lds double-buffered x staging (R5-proven), W1f frags from L2,
// fused transpose+convert, fused sub-chunk affine reduce, and LDS-staged
// packed-AB epilogue (full-line 1KB/wave contiguous stores).
__global__ __launch_bounds__(256, 4) void k_gemm1(const float* __restrict__ x,
        const u16* __restrict__ W1f, const float* __restrict__ B1,
        unsigned* __restrict__ AB,
        float* __restrict__ Ac, float* __restrict__ Bc){
  __shared__ __align__(16) float ls[8192];     // 2 x 16 KB: x chunk fp32 [64 k][64 t]
  __shared__ __align__(16) u16  xs[4096];      // 8 KB: [c 0..3][ks 0..1][lane][8]
  const int tid = threadIdx.x;
  const int wv = tid >> 6, L = tid & 63;
  const int q = L >> 4, ln = L & 15;
  const int hw = blockIdx.x;
  const int g = (hw & 7)*128 + (hw >> 3);      // XCD cluster: 1024%8==0, bijective
  const int F0 = g * 64;
  const int rt0 = 2*wv;
  const bf16x8* W1f8 = (const bf16x8*)W1f;

  f32x4 acc[4][4];
  #pragma unroll
  for (int a=0;a<4;a++)
    #pragma unroll
    for (int c=0;c<4;c++) acc[a][c] = (f32x4){0.f,0.f,0.f,0.f};

  // prologue: stage ck=0 -> buf0 (16 KB, 4 x 1 KB per wave; dest wave-uniform)
  #pragma unroll
  for (int i=0;i<4;i++){
    int seg = wv*4 + i;
    __builtin_amdgcn_global_load_lds(
      AS1(x + (size_t)(seg*4 + q)*NF + F0 + ln*4),
      AS3(ls + seg*256), 16, 0, 0);
  }

  for (int ck=0; ck<8; ++ck){
    __syncthreads();                           // stage(ck) landed
    // issue next stage into the OTHER buffer; overlaps transpose below.
    if (ck < 7){
      #pragma unroll
      for (int i=0;i<4;i++){
        int seg = wv*4 + i;
        __builtin_amdgcn_global_load_lds(
          AS1(x + (size_t)((ck+1)*64 + seg*4 + q)*NF + F0 + ln*4),
          AS3(ls + ((ck+1)&1)*4096 + seg*256), 16, 0, 0);
      }
    }
    // W1 fragments straight from L2 (W1f is 256 KB, hot)
    bf16x8 af[2][4];
    #pragma unroll
    for (int ks=0;ks<2;ks++){
      af[ks][0] = W1f8[ck*2048 + ((rt0  )*2+ks)*64 + L];
      af[ks][1] = W1f8[ck*2048 + ((rt0+1)*2+ks)*64 + L];
      af[ks][2] = W1f8[ck*2048 + ((rt0+8)*2+ks)*64 + L];
      af[ks][3] = W1f8[ck*2048 + ((rt0+9)*2+ks)*64 + L];
    }
    // transpose-convert ls[ck&1] -> xs; 2 slots/thread, 8 elems each
    {
      const float* lsb = ls + (ck&1)*4096;
      #pragma unroll
      for (int i=0;i<2;i++){
        int s    = tid + 256*i;
        int lns  = s & 15;
        int cc   = (s >> 4) & 3;
        int qs   = (s >> 6) & 3;
        int kss  = (s >> 8) & 1;
        const float* rp = lsb + (kss*32 + qs*8)*64 + cc*16 + lns;
        unsigned u[8];
        #pragma unroll
        for (int j=0;j<8;j++) u[j] = f2bf(rp[j*64]);
        uint4 pk;
        pk.x = u[0] | (u[1]<<16); pk.y = u[2] | (u[3]<<16);
        pk.z = u[4] | (u[5]<<16); pk.w = u[6] | (u[7]<<16);
        *(uint4*)(xs + ((cc*2+kss)*64 + qs*16 + lns)*8) = pk;
      }
    }
    __syncthreads();                           // xs ready (drains stage(ck+1) too)
    #pragma unroll
    for (int ks=0; ks<2; ++ks){
      #pragma unroll
      for (int c=0;c<4;c++){
        bf16x8 bf = ((const bf16x8*)xs)[(c*2+ks)*64 + L];
        acc[0][c] = __builtin_amdgcn_mfma_f32_16x16x32_bf16(af[ks][0], bf, acc[0][c], 0,0,0);
        acc[1][c] = __builtin_amdgcn_mfma_f32_16x16x32_bf16(af[ks][1], bf, acc[1][c], 0,0,0);
        acc[2][c] = __builtin_amdgcn_mfma_f32_16x16x32_bf16(af[ks][2], bf, acc[2][c], 0,0,0);
        acc[3][c] = __builtin_amdgcn_mfma_f32_16x16x32_bf16(af[ks][3], bf, acc[3][c], 0,0,0);
      }
    }
  }

  // epilogue: sigmoid, a=le*ri, b=1-le; pack bf16 pair -> LDS (swizzled), fused
  // reduce from the ROUNDED values (consistent with k_apply's recompute).
  __syncthreads();                             // all ls reads done; reuse as lsu
  unsigned* lsu = (unsigned*)ls;               // [t' 0..63][col 0..127] u32
  float bl[2][4], br[2][4], RA[2][4], RB[2][4];
  #pragma unroll
  for (int pr=0;pr<2;pr++){
    int mb = 32*wv + 16*pr + 4*q;
    #pragma unroll
    for (int r=0;r<4;r++){ bl[pr][r] = B1[mb+r]; br[pr][r] = B1[mb+128+r]; }
  }
  #pragma unroll
  for (int c=0;c<4;c++){
    int tp = 16*c + ln;                        // local t'
    #pragma unroll
    for (int pr=0;pr<2;pr++){
      int mb = 32*wv + 16*pr + 4*q;
      f32x4 Lv = acc[pr][c], Rv = acc[pr+2][c];
      unsigned p4[4];
      #pragma unroll
      for (int r=0;r<4;r++){
        float le = sigm(Lv[r] + bl[pr][r]);
        float ri = sigm(Rv[r] + br[pr][r]);
        p4[r] = (unsigned)f2bf(le*ri) | (((unsigned)f2bf(1.0f - le))<<16);
      }
      *(uint4*)(&lsu[tp*128 + (mb ^ (ln<<2))]) = make_uint4(p4[0],p4[1],p4[2],p4[3]);
      #pragma unroll
      for (int r=0;r<4;r++){
        float As = bfl(p4[r]), Bs = bfh(p4[r]);
        #pragma unroll
        for (int d=1; d<16; d<<=1){
          float Ap = __shfl_xor(As, d);
          float Bp = __shfl_xor(Bs, d);
          Bs = (ln & d) ? fmaf(As, Bp, Bs) : fmaf(Ap, Bs, Bp);
          As *= Ap;
        }
        if (c == 0){ RA[pr][r] = As; RB[pr][r] = Bs; }
        else       { RB[pr][r] = fmaf(As, RB[pr][r], Bs); RA[pr][r] *= As; }
      }
    }
  }
  if (ln == 0){
    #pragma unroll
    for (int pr=0;pr<2;pr++){
      int mb = 32*wv + 16*pr + 4*q;
      #pragma unroll
      for (int r=0;r<4;r++){
        Ac[g*128 + mb + r] = RA[pr][r];
        Bc[g*128 + mb + r] = RB[pr][r];
      }
    }
  }
  __syncthreads();                             // lsu complete
  // linear copy-out: 8 x 1KB/wave contiguous stores (full-line coverage)
  {
    unsigned* dst = AB + (size_t)g*8192;
    #pragma unroll
    for (int k2=0;k2<8;k2++){
      int i  = tid + 256*k2;                   // uint4 slot 0..2047
      int t2 = i >> 5;
      int mm = (i & 31) << 2;
      uint4 v = *(const uint4*)(&lsu[t2*128 + (mm ^ ((t2&15)<<2))]);
      *(uint4*)(dst + (size_t)i*4) = v;
    }
  }
}

// ---------------- macro totals: 16 blocks, each composes 64 sub-chunks
__global__ __launch_bounds__(256) void k_scan(const float* __restrict__ Ac, const float* __restrict__ Bc,
                                              float* __restrict__ MtA, float* __restrict__ MtB){
  __shared__ float sA[2][128], sB[2][128];
  const int j = blockIdx.x;
  const int m = threadIdx.x & 127, s4 = threadIdx.x >> 7;
  const int c0 = j*64 + s4*32;
  float A = 1.f, B = 0.f;
  #pragma unroll 8
  for (int i=0;i<32;i++){
    float a = Ac[(c0+i)*128 + m], b = Bc[(c0+i)*128 + m];
    B = fmaf(a, B, b);
    A *= a;
  }
  sA[s4][m] = A; sB[s4][m] = B;
  __syncthreads();
  if (s4 == 0){
    MtA[j*128+m] = sA[1][m] * sA[0][m];
    MtB[j*128+m] = fmaf(sA[1][m], sB[0][m], sB[1][m]);
  }
}

// ---------------- apply: 64 frames per block, grid 1024, XCD-clustered.
// phase 0: macro-prefix + in-macro scan; phase 1: z recompute from packed AB;
// GEMM2 + epilogue.
__global__ __launch_bounds__(256, 4) void k_apply(const unsigned* __restrict__ AB,
        const float* __restrict__ Ac, const float* __restrict__ Bc,
        const float* __restrict__ MtA, const float* __restrict__ MtB,
        const u16* __restrict__ W2f, const float* __restrict__ B2,
        float* __restrict__ out){
  __shared__ __align__(16) u16 zf[8192];       // 16 KB: [c 0..3][ks 0..3][lane][8]
  __shared__ float sA[2][128], sB[2][128];
  const int tid = threadIdx.x;
  const int hw = blockIdx.x;
  const int g = (hw & 7)*128 + (hw >> 3);      // XCD cluster
  const int T0 = g*64;
  const int m = tid & 127, s4 = tid >> 7;

  // phase 0: value entering sub-chunk g
  float vg;
  {
    const int j = g >> 6, r0 = j << 6, n = g & 63;
    int c0 = r0 + s4*32, c1 = r0 + n; if (c1 > c0+32) c1 = c0+32;
    float A = 1.f, B = 0.f;
    for (int c = c0; c < c1; ++c){
      float a = Ac[c*128 + m], b = Bc[c*128 + m];
      B = fmaf(a, B, b);
      A *= a;
    }
    sA[s4][m] = A; sB[s4][m] = B;              // empty segment = identity
    float v = 0.f;
    for (int jj=0; jj<j; ++jj) v = fmaf(MtA[jj*128+m], v, MtB[jj*128+m]);
    __syncthreads();
    v = fmaf(sA[0][m], v, sB[0][m]);
    v = fmaf(sA[1][m], v, sB[1][m]);
    vg = v;
    __syncthreads();                           // before sA/sB reuse
  }

  // phase 1: thread (m, s4) owns frames [32*s4, 32*s4+32) of this sub-chunk
  {
    const unsigned* abp = AB + (size_t)(T0 + s4*32)*128 + m;
    unsigned abreg[32];
    #pragma unroll
    for (int i=0;i<32;i++) abreg[i] = abp[(size_t)i*128];
    float A = 1.f, Bv = 0.f;
    #pragma unroll
    for (int i=0;i<32;i++){ Bv = fmaf(bfl(abreg[i]), Bv, bfh(abreg[i])); A *= bfl(abreg[i]); }
    sA[s4][m] = A; sB[s4][m] = Bv;
    __syncthreads();
    float v = vg;
    if (s4 == 1) v = fmaf(sA[0][m], v, sB[0][m]);
    const int base_m = (m>>5)*512 + ((m>>3)&3)*128 + (m&7);
    #pragma unroll
    for (int i=0;i<32;i++){
      int t = s4*32 + i;
      zf[base_m + (t>>4)*2048 + (t&15)*8] = f2bf(v);
      v = fmaf(bfl(abreg[i]), v, bfh(abreg[i]));
    }
  }
  __syncthreads();

  // GEMM2: 4 waves x 4 row-tiles each x 4 c-tiles, K=128
  const int wv = tid >> 6, L = tid & 63;
  const int q = L >> 4, ln = L & 15;
  f32x4 acc[4][4];
  #pragma unroll
  for (int a=0;a<4;a++)
    #pragma unroll
    for (int c=0;c<4;c++) acc[a][c] = (f32x4){0.f,0.f,0.f,0.f};

  #pragma unroll
  for (int ks=0; ks<4; ++ks){
    bf16x8 af[4];
    #pragma unroll
    for (int a=0;a<4;a++) af[a] = ((const bf16x8*)W2f)[((4*wv+a)*4+ks)*64 + L]; // L2-hot
    #pragma unroll
    for (int c=0;c<4;c++){
      bf16x8 bf = ((const bf16x8*)zf)[(c*4+ks)*64 + L];
      #pragma unroll
      for (int a=0;a<4;a++)
        acc[a][c] = __builtin_amdgcn_mfma_f32_16x16x32_bf16(af[a], bf, acc[a][c], 0,0,0);
    }
  }

  #pragma unroll
  for (int a=0;a<4;a++){
    int rowb = (4*wv+a)*16 + q*4;
    float b2[4];
    #pragma unroll
    for (int r=0;r<4;r++) b2[r] = B2[rowb+r];
    #pragma unroll
    for (int r=0;r<4;r++){
      #pragma unroll
      for (int c=0;c<4;c++)
        out[(size_t)(rowb+r)*NF + T0 + 16*c + ln] = sigm(-(acc[a][c][r] + b2[r]));
    }
  }
}

extern "C" void kernel_launch(void* const* d_in, const int* in_sizes, int n_in,
                              void* d_out, int out_size, void* d_ws, size_t ws_size,
                              hipStream_t stream) {
  const float* x  = (const float*)d_in[0];   // (512, 65536)
  const float* W1 = (const float*)d_in[1];   // (256, 512)
  const float* B1 = (const float*)d_in[2];   // (256, 1)
  const float* W2 = (const float*)d_in[3];   // (256, 128)
  const float* B2 = (const float*)d_in[4];   // (256, 1)
  float* out = (float*)d_out;                // (256, 65536) = 64 MB

  u16*      W1f = (u16*)d_ws;                // 131072 u16 (256 KB)
  u16*      W2f = W1f + 131072;              // 32768 u16 (64 KB)
  unsigned* AB  = (unsigned*)d_ws + 81920;   // NF*128 u32 = 32 MB
  float*    Ac  = (float*)(AB + (size_t)NF*128);  // 1024*128
  float*    Bc  = Ac + (size_t)NSC*128;
  float*    MtA = Bc + (size_t)NSC*128;      // 16*128
  float*    MtB = MtA + (size_t)NMAC*128;

  k_prep <<<512, 256, 0, stream>>>(W1, W2, W1f, W2f);
  k_gemm1<<<NSC, 256, 0, stream>>>(x, W1f, B1, AB, Ac, Bc);
  k_scan <<<NMAC, 256, 0, stream>>>(Ac, Bc, MtA, MtB);
  k_apply<<<NSC, 256, 0, stream>>>(AB, Ac, Bc, MtA, MtB, W2f, B2, out);
}